// Round 6
// baseline (1396.624 us; speedup 1.0000x reference)
//
#include <hip/hip_runtime.h>
#include <hip/hip_bf16.h>
#include <math.h>

typedef unsigned short u16;
typedef __attribute__((ext_vector_type(8))) short frag8;
typedef __attribute__((ext_vector_type(4))) float f32x4;
typedef __attribute__((ext_vector_type(8))) unsigned short us8;
typedef __attribute__((ext_vector_type(4))) unsigned short us4;

#define B_ 8
#define C_ 512
#define D_ 512
#define N_ 4096

__device__ __forceinline__ float b2f(u16 u){ union { unsigned int i; float f; } v; v.i = ((unsigned int)u) << 16; return v.f; }
__device__ __forceinline__ u16 f2b(float f){ union { float f; unsigned int i; } v; v.f = f; unsigned int x = v.i; return (u16)((x + 0x7fffu + ((x >> 16) & 1u)) >> 16); }
__device__ __forceinline__ float sigm(float x){ return 1.0f / (1.0f + __expf(-x)); }

// load 8 consecutive elements as bf16 from fp32 (fl=1) or bf16 (fl=0) source
__device__ __forceinline__ us8 load_x8(const void* __restrict__ x, int fl, size_t off){
    if (fl){
        const float* p = (const float*)x + off;
        f32x4 a = *(const f32x4*)p;
        f32x4 b = *(const f32x4*)(p + 4);
        us8 o;
        #pragma unroll
        for (int j = 0; j < 4; ++j){ o[j] = f2b(a[j]); o[4 + j] = f2b(b[j]); }
        return o;
    }
    return *(const us8*)((const u16*)x + off);
}

// ---------------- dtype detect: bf16 vs fp32 ----------------
__global__ __launch_bounds__(256) void k_detect(const unsigned int* __restrict__ x, int* __restrict__ flag){
    int tid = threadIdx.x;
    unsigned int w = x[tid];
    int e = (int)((w >> 7) & 0xFFu);
    int in = (e >= 100 && e <= 140) ? 1 : 0;
    __shared__ int sm[4];
    for (int off = 32; off > 0; off >>= 1) in += __shfl_down(in, off);
    if ((tid & 63) == 0) sm[tid >> 6] = in;
    __syncthreads();
    if (tid == 0) *flag = ((sm[0] + sm[1] + sm[2] + sm[3]) < 128) ? 1 : 0;  // 1 = fp32
}

__global__ __launch_bounds__(256) void k_convert(const void* __restrict__ src, u16* __restrict__ dst,
                                                 int n, const int* __restrict__ flag){
    int i = (blockIdx.x * 256 + threadIdx.x) * 8;
    if (i >= n) return;
    *(us8*)(dst + i) = load_x8(src, *flag, (size_t)i);
}

// ---------------- mx[k] = mean over (b,n) of x ----------------
__global__ __launch_bounds__(256) void k_xmean(const void* __restrict__ x, const int* __restrict__ flag,
                                               float* __restrict__ mx){
    int k = blockIdx.x, tid = threadIdx.x, fl = *flag;
    float sum = 0.f;
    for (int b = 0; b < B_; ++b){
        size_t base = ((size_t)b * C_ + k) * N_;
        for (int i = tid * 8; i < N_; i += 2048){
            us8 v = load_x8(x, fl, base + i);
            #pragma unroll
            for (int j = 0; j < 8; ++j) sum += b2f(v[j]);
        }
    }
    __shared__ float sm[4];
    for (int off = 32; off > 0; off >>= 1) sum += __shfl_down(sum, off);
    if ((tid & 63) == 0) sm[tid >> 6] = sum;
    __syncthreads();
    if (tid == 0) mx[k] = (sm[0] + sm[1] + sm[2] + sm[3]) * (1.0f / 32768.0f);
}

// ---------------- Gram: Gb[k][k'] = E[x_k x_k'] (bf16) ----------------
__global__ __launch_bounds__(256) void k_gram(const void* __restrict__ x, const int* __restrict__ flag,
                                              u16* __restrict__ Gb){
    __shared__ __attribute__((aligned(16))) u16 As[64][40];
    __shared__ __attribute__((aligned(16))) u16 Bs[64][40];
    int k0 = blockIdx.y * 64, kp0 = blockIdx.x * 64;
    int tid = threadIdx.x, row = tid >> 2, cg = (tid & 3) * 8;
    int w = tid >> 6, l = tid & 63, lr = l & 15, q = l >> 4;
    int fl = *flag;
    f32x4 acc[4] = {};
    for (int b = 0; b < B_; ++b){
        size_t abase = ((size_t)b * C_ + k0 + row) * N_ + cg;
        size_t bbase = ((size_t)b * C_ + kp0 + row) * N_ + cg;
        for (int n0 = 0; n0 < N_; n0 += 32){
            *(us8*)&As[row][cg] = load_x8(x, fl, abase + n0);
            *(us8*)&Bs[row][cg] = load_x8(x, fl, bbase + n0);
            __syncthreads();
            frag8 af = *(const frag8*)&As[w * 16 + lr][q * 8];
            #pragma unroll
            for (int t4 = 0; t4 < 4; ++t4){
                frag8 bfv = *(const frag8*)&Bs[t4 * 16 + lr][q * 8];
                acc[t4] = __builtin_amdgcn_mfma_f32_16x16x32_bf16(af, bfv, acc[t4], 0, 0, 0);
            }
            __syncthreads();
        }
    }
    #pragma unroll
    for (int t4 = 0; t4 < 4; ++t4)
        #pragma unroll
        for (int r = 0; r < 4; ++r)
            Gb[(size_t)(k0 + w * 16 + q * 4 + r) * C_ + kp0 + t4 * 16 + lr] = f2b(acc[t4][r] * (1.0f / 32768.0f));
}

// ---------------- T = W * G (fp32 out), G symmetric ----------------
__global__ __launch_bounds__(256) void k_wg(const u16* __restrict__ wc, const u16* __restrict__ Gb, float* __restrict__ T){
    __shared__ __attribute__((aligned(16))) u16 As[64][40];
    __shared__ __attribute__((aligned(16))) u16 Bs[64][40];
    int o0 = blockIdx.y * 64, kp0 = blockIdx.x * 64;
    int tid = threadIdx.x, row = tid >> 2, cg = (tid & 3) * 8;
    const u16* ap = wc + (size_t)(o0 + row) * C_ + cg;
    const u16* bp = Gb + (size_t)(kp0 + row) * C_ + cg;
    int w = tid >> 6, l = tid & 63, lr = l & 15, q = l >> 4;
    f32x4 acc[4] = {};
    for (int k0 = 0; k0 < 512; k0 += 32){
        *(us8*)&As[row][cg] = *(const us8*)(ap + k0);
        *(us8*)&Bs[row][cg] = *(const us8*)(bp + k0);
        __syncthreads();
        frag8 af = *(const frag8*)&As[w * 16 + lr][q * 8];
        #pragma unroll
        for (int t4 = 0; t4 < 4; ++t4){
            frag8 bfv = *(const frag8*)&Bs[t4 * 16 + lr][q * 8];
            acc[t4] = __builtin_amdgcn_mfma_f32_16x16x32_bf16(af, bfv, acc[t4], 0, 0, 0);
        }
        __syncthreads();
    }
    #pragma unroll
    for (int t4 = 0; t4 < 4; ++t4)
        #pragma unroll
        for (int r = 0; r < 4; ++r)
            T[(size_t)(o0 + w * 16 + q * 4 + r) * C_ + kp0 + t4 * 16 + lr] = acc[t4][r];
}

// ---------------- BN1 finalize ----------------
__global__ __launch_bounds__(256) void k_bn1fin(const float* __restrict__ T, const u16* __restrict__ wc,
                                                const float* __restrict__ mx, const u16* __restrict__ g1,
                                                const u16* __restrict__ b1, float* __restrict__ s1,
                                                float* __restrict__ t1){
    int o = blockIdx.x, tid = threadIdx.x;
    float e2 = 0.f, mn = 0.f;
    for (int k = tid; k < 512; k += 256){
        float wv = b2f(wc[(size_t)o * C_ + k]);
        e2 += T[(size_t)o * C_ + k] * wv;
        mn += wv * mx[k];
    }
    __shared__ float sm[8];
    for (int off = 32; off > 0; off >>= 1){ e2 += __shfl_down(e2, off); mn += __shfl_down(mn, off); }
    int w = tid >> 6;
    if ((tid & 63) == 0){ sm[w] = e2; sm[4 + w] = mn; }
    __syncthreads();
    if (tid == 0){
        float E2 = sm[0] + sm[1] + sm[2] + sm[3];
        float M  = sm[4] + sm[5] + sm[6] + sm[7];
        float var = E2 - M * M;
        float inv = rsqrtf(var + 1e-5f);
        float sc = b2f(g1[o]) * inv;
        s1[o] = sc;
        t1[o] = b2f(b1[o]) - M * sc;
    }
}

// ---------------- GEMM1 phase (batched), fused BN + activation ----------------
// PHASE 1: c0 = 512+by*64 -> dst rows [0,512)=sigm(k), [512,1024)=v
// PHASE 2: by<8: c0=by*64 (sigm(q), rows c) ; by>=8: c0=1536+(by-8)*64 (silu(g), rows c-1024)
template<int PHASE>
__global__ __launch_bounds__(256) void k_gemm_act(const u16* __restrict__ wc, const void* __restrict__ x,
                                                  const int* __restrict__ flag,
                                                  const float* __restrict__ s1, const float* __restrict__ t1,
                                                  u16* __restrict__ dst){
    __shared__ __attribute__((aligned(16))) u16 As[64][40];
    __shared__ __attribute__((aligned(16))) u16 Xs[32][72];
    int b = blockIdx.z, n0 = blockIdx.x * 64, by = blockIdx.y;
    int c0 = (PHASE == 1) ? (512 + by * 64) : ((by < 8) ? by * 64 : 1536 + (by - 8) * 64);
    int tid = threadIdx.x;
    int arow = tid >> 2, acg = (tid & 3) * 8;
    int xrow = tid >> 3, xcg = (tid & 7) * 8;
    const u16* wp = wc + (size_t)(c0 + arow) * C_ + acg;
    int fl = *flag;
    int w = tid >> 6, l = tid & 63, lr = l & 15, q = l >> 4;
    f32x4 acc[4] = {};
    for (int k0 = 0; k0 < 512; k0 += 32){
        *(us8*)&As[arow][acg] = *(const us8*)(wp + k0);
        *(us8*)&Xs[xrow][xcg] = load_x8(x, fl, ((size_t)b * C_ + k0 + xrow) * N_ + n0 + xcg);
        __syncthreads();
        frag8 bfv;
        #pragma unroll
        for (int j = 0; j < 8; ++j) bfv[j] = (short)Xs[q * 8 + j][w * 16 + lr];
        #pragma unroll
        for (int t4 = 0; t4 < 4; ++t4){
            frag8 af = *(const frag8*)&As[t4 * 16 + lr][q * 8];
            acc[t4] = __builtin_amdgcn_mfma_f32_16x16x32_bf16(af, bfv, acc[t4], 0, 0, 0);
        }
        __syncthreads();
    }
    int n = n0 + w * 16 + lr;
    #pragma unroll
    for (int t4 = 0; t4 < 4; ++t4){
        #pragma unroll
        for (int r = 0; r < 4; ++r){
            int c = c0 + t4 * 16 + q * 4 + r;
            float ybn = acc[t4][r] * s1[c] + t1[c];
            float ov = (c < 1024) ? sigm(ybn) : ((c < 1536) ? ybn : ybn * sigm(ybn));
            int local = (PHASE == 1) ? (c - 512) : ((c < 512) ? c : c - 1024);
            dst[((size_t)b * 1024 + local) * N_ + n] = f2b(ov);
        }
    }
}

// ---------------- vk[b][d][e] = (1/N) sum_n v[d][n] * k[e][n] ----------------
__global__ __launch_bounds__(256) void k_vk(const u16* __restrict__ kv, u16* __restrict__ vk){
    __shared__ __attribute__((aligned(16))) u16 As[64][40];
    __shared__ __attribute__((aligned(16))) u16 Bs[64][40];
    int b = blockIdx.z, d0 = blockIdx.y * 64, e0 = blockIdx.x * 64;
    int tid = threadIdx.x, row = tid >> 2, cg = (tid & 3) * 8;
    const u16* vp = kv + ((size_t)b * 1024 + 512 + d0 + row) * N_ + cg;
    const u16* kp = kv + ((size_t)b * 1024 + e0 + row) * N_ + cg;
    int w = tid >> 6, l = tid & 63, lr = l & 15, q = l >> 4;
    f32x4 acc[4] = {};
    for (int n0 = 0; n0 < N_; n0 += 32){
        *(us8*)&As[row][cg] = *(const us8*)(vp + n0);
        *(us8*)&Bs[row][cg] = *(const us8*)(kp + n0);
        __syncthreads();
        frag8 af = *(const frag8*)&As[w * 16 + lr][q * 8];
        #pragma unroll
        for (int t4 = 0; t4 < 4; ++t4){
            frag8 bfv = *(const frag8*)&Bs[t4 * 16 + lr][q * 8];
            acc[t4] = __builtin_amdgcn_mfma_f32_16x16x32_bf16(af, bfv, acc[t4], 0, 0, 0);
        }
        __syncthreads();
    }
    #pragma unroll
    for (int t4 = 0; t4 < 4; ++t4)
        #pragma unroll
        for (int r = 0; r < 4; ++r)
            vk[((size_t)b * D_ + d0 + w * 16 + q * 4 + r) * D_ + e0 + t4 * 16 + lr] = f2b(acc[t4][r] * (1.0f / 4096.0f));
}

// ---------------- kmean[b][d] = mean_n k[d][n] ----------------
__global__ __launch_bounds__(256) void k_kmean(const u16* __restrict__ kv, u16* __restrict__ kmean){
    int b = blockIdx.y, d = blockIdx.x, tid = threadIdx.x;
    const u16* p = kv + ((size_t)b * 1024 + d) * N_;
    float sum = 0.f;
    for (int i = tid * 8; i < N_; i += 2048){
        us8 v = *(const us8*)(p + i);
        #pragma unroll
        for (int j = 0; j < 8; ++j) sum += b2f(v[j]);
    }
    __shared__ float sm[4];
    for (int off = 32; off > 0; off >>= 1) sum += __shfl_down(sum, off);
    if ((tid & 63) == 0) sm[tid >> 6] = sum;
    __syncthreads();
    if (tid == 0) kmean[b * D_ + d] = f2b((sm[0] + sm[1] + sm[2] + sm[3]) * (1.0f / 4096.0f));
}

// ---------------- attn + RMS + gate -> og (B, N, D) ----------------
__global__ __launch_bounds__(256, 1) void k_attn(const u16* __restrict__ qg, const u16* __restrict__ vk,
                                                 const u16* __restrict__ kmean, const u16* __restrict__ anw,
                                                 u16* __restrict__ og){
    __shared__ __attribute__((aligned(16))) u16 Qs[32][64];
    __shared__ float zbuf[64];
    __shared__ float sm_aw[512];
    int b = blockIdx.y, n0 = blockIdx.x * 64, tid = threadIdx.x;
    for (int i = tid; i < 512; i += 256) sm_aw[i] = b2f(anw[i]);
    int row = tid >> 3, cg = (tid & 7) * 8;
    int w = tid >> 6, l = tid & 63, lr = l & 15, q = l >> 4;
    f32x4 acc[32];
    #pragma unroll
    for (int i = 0; i < 32; ++i) acc[i] = (f32x4){0.f, 0.f, 0.f, 0.f};
    f32x4 accz = {};
    const u16* vkb = vk + (size_t)b * D_ * D_;
    __syncthreads();
    for (int e0 = 0; e0 < 512; e0 += 32){
        *(us8*)&Qs[row][cg] = *(const us8*)(qg + ((size_t)b * 1024 + e0 + row) * N_ + n0 + cg);
        __syncthreads();
        frag8 bfv;
        #pragma unroll
        for (int j = 0; j < 8; ++j) bfv[j] = (short)Qs[q * 8 + j][w * 16 + lr];
        frag8 zf = {};
        if (lr == 0) zf = *(const frag8*)(kmean + (size_t)b * D_ + e0 + q * 8);
        accz = __builtin_amdgcn_mfma_f32_16x16x32_bf16(zf, bfv, accz, 0, 0, 0);
        #pragma unroll
        for (int t4 = 0; t4 < 32; ++t4){
            frag8 af = *(const frag8*)(vkb + (size_t)(t4 * 16 + lr) * D_ + e0 + q * 8);
            acc[t4] = __builtin_amdgcn_mfma_f32_16x16x32_bf16(af, bfv, acc[t4], 0, 0, 0);
        }
        __syncthreads();
    }
    if (l < 16) zbuf[w * 16 + l] = accz[0] + 0.0005f;
    __syncthreads();
    float rz = 1.0f / zbuf[w * 16 + lr];
    float ssq = 0.f;
    #pragma unroll
    for (int t4 = 0; t4 < 32; ++t4)
        #pragma unroll
        for (int r = 0; r < 4; ++r){ float a = acc[t4][r] * rz; acc[t4][r] = a; ssq += a * a; }
    ssq += __shfl_xor(ssq, 16);
    ssq += __shfl_xor(ssq, 32);
    float rinv = rsqrtf(ssq * (1.0f / 512.0f) + 1e-6f);
    int n = n0 + w * 16 + lr;
    #pragma unroll
    for (int t4 = 0; t4 < 32; ++t4){
        us4 o4;
        #pragma unroll
        for (int r = 0; r < 4; ++r){
            int d = t4 * 16 + q * 4 + r;
            float gate = b2f(qg[((size_t)b * 1024 + 512 + d) * N_ + n]);   // silu already applied
            o4[r] = f2b(acc[t4][r] * rinv * sm_aw[d] * gate);
        }
        *(us4*)(og + ((size_t)b * N_ + n) * D_ + t4 * 16 + q * 4) = o4;
    }
}

// ---------------- proj: po[b][c][n] = sum_d P[c][d] * og[b][n][d] (fp32 out) ----------------
__global__ __launch_bounds__(256) void k_proj(const u16* __restrict__ P, const u16* __restrict__ og, float* __restrict__ po){
    __shared__ __attribute__((aligned(16))) u16 As[64][40];
    __shared__ __attribute__((aligned(16))) u16 Bs[64][40];
    int b = blockIdx.z, c0 = blockIdx.y * 64, n0 = blockIdx.x * 64;
    int tid = threadIdx.x, row = tid >> 2, cg = (tid & 3) * 8;
    const u16* pp = P + (size_t)(c0 + row) * D_ + cg;
    const u16* op = og + ((size_t)b * N_ + n0 + row) * D_ + cg;
    int w = tid >> 6, l = tid & 63, lr = l & 15, q = l >> 4;
    f32x4 acc[4] = {};
    for (int k0 = 0; k0 < 512; k0 += 32){
        *(us8*)&As[row][cg] = *(const us8*)(pp + k0);
        *(us8*)&Bs[row][cg] = *(const us8*)(op + k0);
        __syncthreads();
        frag8 af = *(const frag8*)&As[w * 16 + lr][q * 8];
        #pragma unroll
        for (int t4 = 0; t4 < 4; ++t4){
            frag8 bfv = *(const frag8*)&Bs[t4 * 16 + lr][q * 8];
            acc[t4] = __builtin_amdgcn_mfma_f32_16x16x32_bf16(af, bfv, acc[t4], 0, 0, 0);
        }
        __syncthreads();
    }
    #pragma unroll
    for (int t4 = 0; t4 < 4; ++t4)
        #pragma unroll
        for (int r = 0; r < 4; ++r)
            po[((size_t)b * C_ + c0 + w * 16 + q * 4 + r) * N_ + n0 + t4 * 16 + lr] = acc[t4][r];
}

// ---------------- BN2 stats (fp32 input) ----------------
__global__ __launch_bounds__(256) void k_bnstats(const float* __restrict__ y, const u16* __restrict__ gamma,
                                                 const u16* __restrict__ beta, float* __restrict__ s,
                                                 float* __restrict__ t){
    int ch = blockIdx.x, tid = threadIdx.x;
    float sum = 0.f, ss = 0.f;
    for (int b = 0; b < B_; ++b){
        const float* p = y + ((size_t)b * C_ + ch) * N_;
        for (int i = tid * 4; i < N_; i += 1024){
            f32x4 v = *(const f32x4*)(p + i);
            #pragma unroll
            for (int j = 0; j < 4; ++j){ sum += v[j]; ss += v[j] * v[j]; }
        }
    }
    __shared__ float sm[8];
    for (int off = 32; off > 0; off >>= 1){ sum += __shfl_down(sum, off); ss += __shfl_down(ss, off); }
    int w = tid >> 6;
    if ((tid & 63) == 0){ sm[w] = sum; sm[4 + w] = ss; }
    __syncthreads();
    if (tid == 0){
        float S = sm[0] + sm[1] + sm[2] + sm[3];
        float Q = sm[4] + sm[5] + sm[6] + sm[7];
        float mean = S / 32768.f;
        float var = Q / 32768.f - mean * mean;
        float inv = rsqrtf(var + 1e-5f);
        float sc = b2f(gamma[ch]) * inv;
        s[ch] = sc;
        t[ch] = b2f(beta[ch]) - mean * sc;
    }
}

// ---------------- apply BN2 in place (fp32) ----------------
__global__ __launch_bounds__(256) void k_bnapply(float* __restrict__ po, const float* __restrict__ s,
                                                 const float* __restrict__ t){
    size_t idx = ((size_t)blockIdx.x * 256 + threadIdx.x) * 8;
    int c = (int)((idx >> 12) & 511);
    float sc = s[c], tc = t[c];
    f32x4 a = *(const f32x4*)(po + idx);
    f32x4 b = *(const f32x4*)(po + idx + 4);
    #pragma unroll
    for (int j = 0; j < 4; ++j){ a[j] = a[j] * sc + tc; b[j] = b[j] * sc + tc; }
    *(f32x4*)(po + idx) = a;
    *(f32x4*)(po + idx + 4) = b;
}

extern "C" void kernel_launch(void* const* d_in, const int* in_sizes, int n_in,
                              void* d_out, int out_size, void* d_ws, size_t ws_size,
                              hipStream_t stream){
    float* out = (float*)d_out;
    char* ws = (char*)d_ws;

    // ---- workspace layout, 108 MB total (ws >= 168 MB demonstrated in r2) ----
    int*   flag  = (int*)ws;
    float* s1    = (float*)(ws + 4096);
    float* t1    = (float*)(ws + 12288);
    float* s2    = (float*)(ws + 20480);
    float* t2    = (float*)(ws + 22528);
    float* mx    = (float*)(ws + 24576);
    u16*   kmean = (u16*)(ws + 28672);                 // 8*512 bf16
    u16*   g1c   = (u16*)(ws + 36864);
    u16*   b1c   = (u16*)(ws + 40960);
    u16*   anwc  = (u16*)(ws + 45056);
    u16*   g2c   = (u16*)(ws + 46080);
    u16*   b2c   = (u16*)(ws + 47104);
    u16*   wc    = (u16*)(ws + (1ull << 20));          // 2 MB
    u16*   pc    = (u16*)(ws + (3ull << 20));          // 0.5 MB
    u16*   Gb    = (u16*)(ws + (3584ull << 10));       // 0.5 MB
    float* T     = (float*)(ws + (4ull << 20));        // 4 MB
    u16*   vkall = (u16*)(ws + (8ull << 20));          // 4 MB
    u16*   kv    = (u16*)(ws + (12ull << 20));         // 64 MB -> ends 76 MB
    u16*   og    = (u16*)(ws + (76ull << 20));         // 32 MB -> ends 108 MB

    // ---- detect + canonicalize params/weights to bf16 ----
    k_detect<<<1, 256, 0, stream>>>((const unsigned int*)d_in[0], flag);
    k_convert<<<512, 256, 0, stream>>>(d_in[1], wc, 1048576, flag);
    k_convert<<<1, 256, 0, stream>>>(d_in[2], g1c, 2048, flag);
    k_convert<<<1, 256, 0, stream>>>(d_in[3], b1c, 2048, flag);
    k_convert<<<1, 256, 0, stream>>>(d_in[4], anwc, 512, flag);
    k_convert<<<128, 256, 0, stream>>>(d_in[5], pc, 262144, flag);
    k_convert<<<1, 256, 0, stream>>>(d_in[6], g2c, 512, flag);
    k_convert<<<1, 256, 0, stream>>>(d_in[7], b2c, 512, flag);

    // ---- BN1 from sufficient statistics ----
    k_xmean<<<512, 256, 0, stream>>>(d_in[0], flag, mx);
    k_gram<<<dim3(8, 8), 256, 0, stream>>>(d_in[0], flag, Gb);
    k_wg<<<dim3(8, 32), 256, 0, stream>>>(wc, Gb, T);
    k_bn1fin<<<2048, 256, 0, stream>>>(T, wc, mx, g1c, b1c, s1, t1);

    // ---- phase 1: k(sigm), v ; vk + kmean ----
    k_gemm_act<1><<<dim3(64, 16, 8), 256, 0, stream>>>(wc, d_in[0], flag, s1, t1, kv);
    k_vk<<<dim3(8, 8, 8), 256, 0, stream>>>(kv, vkall);
    k_kmean<<<dim3(512, 8), 256, 0, stream>>>(kv, kmean);

    // ---- phase 2: q(sigm), g(silu) ; attn ----
    k_gemm_act<2><<<dim3(64, 16, 8), 256, 0, stream>>>(wc, d_in[0], flag, s1, t1, kv);
    k_attn<<<dim3(64, 8), 256, 0, stream>>>(kv, vkall, kmean, anwc, og);

    // ---- proj (fp32 out into d_out) + BN2 in place ----
    k_proj<<<dim3(64, 8, 8), 256, 0, stream>>>(pc, og, out);
    k_bnstats<<<512, 256, 0, stream>>>(out, g2c, b2c, s2, t2);
    k_bnapply<<<8192, 256, 0, stream>>>(out, s2, t2);
}

// Round 7
// 776.604 us; speedup vs baseline: 1.7984x; 1.7984x over previous
//
#include <hip/hip_runtime.h>
#include <hip/hip_bf16.h>
#include <math.h>

typedef unsigned short u16;
typedef __attribute__((ext_vector_type(8))) short frag8;
typedef __attribute__((ext_vector_type(4))) float f32x4;
typedef __attribute__((ext_vector_type(8))) unsigned short us8;
typedef __attribute__((ext_vector_type(4))) unsigned short us4;

#define B_ 8
#define C_ 512
#define D_ 512
#define N_ 4096

__device__ __forceinline__ float b2f(u16 u){ union { unsigned int i; float f; } v; v.i = ((unsigned int)u) << 16; return v.f; }
__device__ __forceinline__ u16 f2b(float f){ union { float f; unsigned int i; } v; v.f = f; unsigned int x = v.i; return (u16)((x + 0x7fffu + ((x >> 16) & 1u)) >> 16); }
__device__ __forceinline__ float sigm(float x){ return 1.0f / (1.0f + __expf(-x)); }

// load 8 consecutive elements as bf16 from fp32 (fl=1) or bf16 (fl=0) source
__device__ __forceinline__ us8 load_x8(const void* __restrict__ x, int fl, size_t off){
    if (fl){
        const float* p = (const float*)x + off;
        f32x4 a = *(const f32x4*)p;
        f32x4 b = *(const f32x4*)(p + 4);
        us8 o;
        #pragma unroll
        for (int j = 0; j < 4; ++j){ o[j] = f2b(a[j]); o[4 + j] = f2b(b[j]); }
        return o;
    }
    return *(const us8*)((const u16*)x + off);
}

// ---------------- dtype detect: bf16 vs fp32 ----------------
__global__ __launch_bounds__(256) void k_detect(const unsigned int* __restrict__ x, int* __restrict__ flag){
    int tid = threadIdx.x;
    unsigned int w = x[tid];
    int e = (int)((w >> 7) & 0xFFu);
    int in = (e >= 100 && e <= 140) ? 1 : 0;
    __shared__ int sm[4];
    for (int off = 32; off > 0; off >>= 1) in += __shfl_down(in, off);
    if ((tid & 63) == 0) sm[tid >> 6] = in;
    __syncthreads();
    if (tid == 0) *flag = ((sm[0] + sm[1] + sm[2] + sm[3]) < 128) ? 1 : 0;  // 1 = fp32
}

__global__ __launch_bounds__(256) void k_convert(const void* __restrict__ src, u16* __restrict__ dst,
                                                 int n, const int* __restrict__ flag){
    int i = (blockIdx.x * 256 + threadIdx.x) * 8;
    if (i >= n) return;
    *(us8*)(dst + i) = load_x8(src, *flag, (size_t)i);
}

// ---------------- mx[k] = mean over (b,n) of x ----------------
__global__ __launch_bounds__(256) void k_xmean(const void* __restrict__ x, const int* __restrict__ flag,
                                               float* __restrict__ mx){
    int k = blockIdx.x, tid = threadIdx.x, fl = *flag;
    float sum = 0.f;
    for (int b = 0; b < B_; ++b){
        size_t base = ((size_t)b * C_ + k) * N_;
        for (int i = tid * 8; i < N_; i += 2048){
            us8 v = load_x8(x, fl, base + i);
            #pragma unroll
            for (int j = 0; j < 8; ++j) sum += b2f(v[j]);
        }
    }
    __shared__ float sm[4];
    for (int off = 32; off > 0; off >>= 1) sum += __shfl_down(sum, off);
    if ((tid & 63) == 0) sm[tid >> 6] = sum;
    __syncthreads();
    if (tid == 0) mx[k] = (sm[0] + sm[1] + sm[2] + sm[3]) * (1.0f / 32768.0f);
}

// ---------------- Gram split-K: Gf[k][k'] += partial sum over (b, n-chunk) ----------------
// grid (8 kp, 8 k, 32 splits): split s -> b = s>>2, n-chunk = (s&3)*1024
__global__ __launch_bounds__(256) void k_gram_split(const void* __restrict__ x, const int* __restrict__ flag,
                                                    float* __restrict__ Gf){
    __shared__ __attribute__((aligned(16))) u16 As[64][40];
    __shared__ __attribute__((aligned(16))) u16 Bs[64][40];
    int k0 = blockIdx.y * 64, kp0 = blockIdx.x * 64;
    int s = blockIdx.z;
    int b = s >> 2, nbase = (s & 3) * 1024;
    int tid = threadIdx.x, row = tid >> 2, cg = (tid & 3) * 8;
    int w = tid >> 6, l = tid & 63, lr = l & 15, q = l >> 4;
    int fl = *flag;
    f32x4 acc[4] = {};
    size_t abase = ((size_t)b * C_ + k0 + row) * N_ + nbase + cg;
    size_t bbase = ((size_t)b * C_ + kp0 + row) * N_ + nbase + cg;
    for (int n0 = 0; n0 < 1024; n0 += 32){
        *(us8*)&As[row][cg] = load_x8(x, fl, abase + n0);
        *(us8*)&Bs[row][cg] = load_x8(x, fl, bbase + n0);
        __syncthreads();
        frag8 af = *(const frag8*)&As[w * 16 + lr][q * 8];
        #pragma unroll
        for (int t4 = 0; t4 < 4; ++t4){
            frag8 bfv = *(const frag8*)&Bs[t4 * 16 + lr][q * 8];
            acc[t4] = __builtin_amdgcn_mfma_f32_16x16x32_bf16(af, bfv, acc[t4], 0, 0, 0);
        }
        __syncthreads();
    }
    #pragma unroll
    for (int t4 = 0; t4 < 4; ++t4)
        #pragma unroll
        for (int r = 0; r < 4; ++r)
            atomicAdd(&Gf[(size_t)(k0 + w * 16 + q * 4 + r) * C_ + kp0 + t4 * 16 + lr], acc[t4][r]);
}

// Gf fp32 -> Gb bf16 with 1/32768 scale
__global__ __launch_bounds__(256) void k_gram_fin(const float* __restrict__ Gf, u16* __restrict__ Gb){
    int i = blockIdx.x * 256 + threadIdx.x;
    Gb[i] = f2b(Gf[i] * (1.0f / 32768.0f));
}

// ---------------- T = W * G (fp32 out), G symmetric ----------------
__global__ __launch_bounds__(256) void k_wg(const u16* __restrict__ wc, const u16* __restrict__ Gb, float* __restrict__ T){
    __shared__ __attribute__((aligned(16))) u16 As[64][40];
    __shared__ __attribute__((aligned(16))) u16 Bs[64][40];
    int o0 = blockIdx.y * 64, kp0 = blockIdx.x * 64;
    int tid = threadIdx.x, row = tid >> 2, cg = (tid & 3) * 8;
    const u16* ap = wc + (size_t)(o0 + row) * C_ + cg;
    const u16* bp = Gb + (size_t)(kp0 + row) * C_ + cg;
    int w = tid >> 6, l = tid & 63, lr = l & 15, q = l >> 4;
    f32x4 acc[4] = {};
    for (int k0 = 0; k0 < 512; k0 += 32){
        *(us8*)&As[row][cg] = *(const us8*)(ap + k0);
        *(us8*)&Bs[row][cg] = *(const us8*)(bp + k0);
        __syncthreads();
        frag8 af = *(const frag8*)&As[w * 16 + lr][q * 8];
        #pragma unroll
        for (int t4 = 0; t4 < 4; ++t4){
            frag8 bfv = *(const frag8*)&Bs[t4 * 16 + lr][q * 8];
            acc[t4] = __builtin_amdgcn_mfma_f32_16x16x32_bf16(af, bfv, acc[t4], 0, 0, 0);
        }
        __syncthreads();
    }
    #pragma unroll
    for (int t4 = 0; t4 < 4; ++t4)
        #pragma unroll
        for (int r = 0; r < 4; ++r)
            T[(size_t)(o0 + w * 16 + q * 4 + r) * C_ + kp0 + t4 * 16 + lr] = acc[t4][r];
}

// ---------------- BN1 finalize ----------------
__global__ __launch_bounds__(256) void k_bn1fin(const float* __restrict__ T, const u16* __restrict__ wc,
                                                const float* __restrict__ mx, const u16* __restrict__ g1,
                                                const u16* __restrict__ b1, float* __restrict__ s1,
                                                float* __restrict__ t1){
    int o = blockIdx.x, tid = threadIdx.x;
    float e2 = 0.f, mn = 0.f;
    for (int k = tid; k < 512; k += 256){
        float wv = b2f(wc[(size_t)o * C_ + k]);
        e2 += T[(size_t)o * C_ + k] * wv;
        mn += wv * mx[k];
    }
    __shared__ float sm[8];
    for (int off = 32; off > 0; off >>= 1){ e2 += __shfl_down(e2, off); mn += __shfl_down(mn, off); }
    int w = tid >> 6;
    if ((tid & 63) == 0){ sm[w] = e2; sm[4 + w] = mn; }
    __syncthreads();
    if (tid == 0){
        float E2 = sm[0] + sm[1] + sm[2] + sm[3];
        float M  = sm[4] + sm[5] + sm[6] + sm[7];
        float var = E2 - M * M;
        float inv = rsqrtf(var + 1e-5f);
        float sc = b2f(g1[o]) * inv;
        s1[o] = sc;
        t1[o] = b2f(b1[o]) - M * sc;
    }
}

// ---------------- GEMM1 phase (batched), fused BN + activation ----------------
// PHASE 1: c0 = 512+by*64 -> dst rows [0,512)=sigm(k), [512,1024)=v
// PHASE 2: by<8: c0=by*64 (sigm(q), rows c) ; by>=8: c0=1536+(by-8)*64 (silu(g), rows c-1024)
template<int PHASE>
__global__ __launch_bounds__(256) void k_gemm_act(const u16* __restrict__ wc, const void* __restrict__ x,
                                                  const int* __restrict__ flag,
                                                  const float* __restrict__ s1, const float* __restrict__ t1,
                                                  u16* __restrict__ dst){
    __shared__ __attribute__((aligned(16))) u16 As[64][40];
    __shared__ __attribute__((aligned(16))) u16 Xs[32][72];
    int b = blockIdx.z, n0 = blockIdx.x * 64, by = blockIdx.y;
    int c0 = (PHASE == 1) ? (512 + by * 64) : ((by < 8) ? by * 64 : 1536 + (by - 8) * 64);
    int tid = threadIdx.x;
    int arow = tid >> 2, acg = (tid & 3) * 8;
    int xrow = tid >> 3, xcg = (tid & 7) * 8;
    const u16* wp = wc + (size_t)(c0 + arow) * C_ + acg;
    int fl = *flag;
    int w = tid >> 6, l = tid & 63, lr = l & 15, q = l >> 4;
    f32x4 acc[4] = {};
    for (int k0 = 0; k0 < 512; k0 += 32){
        *(us8*)&As[arow][acg] = *(const us8*)(wp + k0);
        *(us8*)&Xs[xrow][xcg] = load_x8(x, fl, ((size_t)b * C_ + k0 + xrow) * N_ + n0 + xcg);
        __syncthreads();
        frag8 bfv;
        #pragma unroll
        for (int j = 0; j < 8; ++j) bfv[j] = (short)Xs[q * 8 + j][w * 16 + lr];
        #pragma unroll
        for (int t4 = 0; t4 < 4; ++t4){
            frag8 af = *(const frag8*)&As[t4 * 16 + lr][q * 8];
            acc[t4] = __builtin_amdgcn_mfma_f32_16x16x32_bf16(af, bfv, acc[t4], 0, 0, 0);
        }
        __syncthreads();
    }
    int n = n0 + w * 16 + lr;
    #pragma unroll
    for (int t4 = 0; t4 < 4; ++t4){
        #pragma unroll
        for (int r = 0; r < 4; ++r){
            int c = c0 + t4 * 16 + q * 4 + r;
            float ybn = acc[t4][r] * s1[c] + t1[c];
            float ov = (c < 1024) ? sigm(ybn) : ((c < 1536) ? ybn : ybn * sigm(ybn));
            int local = (PHASE == 1) ? (c - 512) : ((c < 512) ? c : c - 1024);
            dst[((size_t)b * 1024 + local) * N_ + n] = f2b(ov);
        }
    }
}

// ---------------- vk[b][d][e] = (1/N) sum_n v[d][n] * k[e][n] ----------------
__global__ __launch_bounds__(256) void k_vk(const u16* __restrict__ kv, u16* __restrict__ vk){
    __shared__ __attribute__((aligned(16))) u16 As[64][40];
    __shared__ __attribute__((aligned(16))) u16 Bs[64][40];
    int b = blockIdx.z, d0 = blockIdx.y * 64, e0 = blockIdx.x * 64;
    int tid = threadIdx.x, row = tid >> 2, cg = (tid & 3) * 8;
    const u16* vp = kv + ((size_t)b * 1024 + 512 + d0 + row) * N_ + cg;
    const u16* kp = kv + ((size_t)b * 1024 + e0 + row) * N_ + cg;
    int w = tid >> 6, l = tid & 63, lr = l & 15, q = l >> 4;
    f32x4 acc[4] = {};
    for (int n0 = 0; n0 < N_; n0 += 32){
        *(us8*)&As[row][cg] = *(const us8*)(vp + n0);
        *(us8*)&Bs[row][cg] = *(const us8*)(kp + n0);
        __syncthreads();
        frag8 af = *(const frag8*)&As[w * 16 + lr][q * 8];
        #pragma unroll
        for (int t4 = 0; t4 < 4; ++t4){
            frag8 bfv = *(const frag8*)&Bs[t4 * 16 + lr][q * 8];
            acc[t4] = __builtin_amdgcn_mfma_f32_16x16x32_bf16(af, bfv, acc[t4], 0, 0, 0);
        }
        __syncthreads();
    }
    #pragma unroll
    for (int t4 = 0; t4 < 4; ++t4)
        #pragma unroll
        for (int r = 0; r < 4; ++r)
            vk[((size_t)b * D_ + d0 + w * 16 + q * 4 + r) * D_ + e0 + t4 * 16 + lr] = f2b(acc[t4][r] * (1.0f / 4096.0f));
}

// ---------------- kmean[b][d] = mean_n k[d][n] ----------------
__global__ __launch_bounds__(256) void k_kmean(const u16* __restrict__ kv, u16* __restrict__ kmean){
    int b = blockIdx.y, d = blockIdx.x, tid = threadIdx.x;
    const u16* p = kv + ((size_t)b * 1024 + d) * N_;
    float sum = 0.f;
    for (int i = tid * 8; i < N_; i += 2048){
        us8 v = *(const us8*)(p + i);
        #pragma unroll
        for (int j = 0; j < 8; ++j) sum += b2f(v[j]);
    }
    __shared__ float sm[4];
    for (int off = 32; off > 0; off >>= 1) sum += __shfl_down(sum, off);
    if ((tid & 63) == 0) sm[tid >> 6] = sum;
    __syncthreads();
    if (tid == 0) kmean[b * D_ + d] = f2b((sm[0] + sm[1] + sm[2] + sm[3]) * (1.0f / 4096.0f));
}

// ---------------- attn + RMS + gate -> og (B, N, D) ----------------
__global__ __launch_bounds__(256, 1) void k_attn(const u16* __restrict__ qg, const u16* __restrict__ vk,
                                                 const u16* __restrict__ kmean, const u16* __restrict__ anw,
                                                 u16* __restrict__ og){
    __shared__ __attribute__((aligned(16))) u16 Qs[32][64];
    __shared__ float zbuf[64];
    __shared__ float sm_aw[512];
    int b = blockIdx.y, n0 = blockIdx.x * 64, tid = threadIdx.x;
    for (int i = tid; i < 512; i += 256) sm_aw[i] = b2f(anw[i]);
    int row = tid >> 3, cg = (tid & 7) * 8;
    int w = tid >> 6, l = tid & 63, lr = l & 15, q = l >> 4;
    f32x4 acc[32];
    #pragma unroll
    for (int i = 0; i < 32; ++i) acc[i] = (f32x4){0.f, 0.f, 0.f, 0.f};
    f32x4 accz = {};
    const u16* vkb = vk + (size_t)b * D_ * D_;
    __syncthreads();
    for (int e0 = 0; e0 < 512; e0 += 32){
        *(us8*)&Qs[row][cg] = *(const us8*)(qg + ((size_t)b * 1024 + e0 + row) * N_ + n0 + cg);
        __syncthreads();
        frag8 bfv;
        #pragma unroll
        for (int j = 0; j < 8; ++j) bfv[j] = (short)Qs[q * 8 + j][w * 16 + lr];
        frag8 zf = {};
        if (lr == 0) zf = *(const frag8*)(kmean + (size_t)b * D_ + e0 + q * 8);
        accz = __builtin_amdgcn_mfma_f32_16x16x32_bf16(zf, bfv, accz, 0, 0, 0);
        #pragma unroll
        for (int t4 = 0; t4 < 32; ++t4){
            frag8 af = *(const frag8*)(vkb + (size_t)(t4 * 16 + lr) * D_ + e0 + q * 8);
            acc[t4] = __builtin_amdgcn_mfma_f32_16x16x32_bf16(af, bfv, acc[t4], 0, 0, 0);
        }
        __syncthreads();
    }
    if (l < 16) zbuf[w * 16 + l] = accz[0] + 0.0005f;
    __syncthreads();
    float rz = 1.0f / zbuf[w * 16 + lr];
    float ssq = 0.f;
    #pragma unroll
    for (int t4 = 0; t4 < 32; ++t4)
        #pragma unroll
        for (int r = 0; r < 4; ++r){ float a = acc[t4][r] * rz; acc[t4][r] = a; ssq += a * a; }
    ssq += __shfl_xor(ssq, 16);
    ssq += __shfl_xor(ssq, 32);
    float rinv = rsqrtf(ssq * (1.0f / 512.0f) + 1e-6f);
    int n = n0 + w * 16 + lr;
    #pragma unroll
    for (int t4 = 0; t4 < 32; ++t4){
        us4 o4;
        #pragma unroll
        for (int r = 0; r < 4; ++r){
            int d = t4 * 16 + q * 4 + r;
            float gate = b2f(qg[((size_t)b * 1024 + 512 + d) * N_ + n]);   // silu already applied
            o4[r] = f2b(acc[t4][r] * rinv * sm_aw[d] * gate);
        }
        *(us4*)(og + ((size_t)b * N_ + n) * D_ + t4 * 16 + q * 4) = o4;
    }
}

// ---------------- proj: po[b][c][n] = sum_d P[c][d] * og[b][n][d] (fp32 out) ----------------
__global__ __launch_bounds__(256) void k_proj(const u16* __restrict__ P, const u16* __restrict__ og, float* __restrict__ po){
    __shared__ __attribute__((aligned(16))) u16 As[64][40];
    __shared__ __attribute__((aligned(16))) u16 Bs[64][40];
    int b = blockIdx.z, c0 = blockIdx.y * 64, n0 = blockIdx.x * 64;
    int tid = threadIdx.x, row = tid >> 2, cg = (tid & 3) * 8;
    const u16* pp = P + (size_t)(c0 + row) * D_ + cg;
    const u16* op = og + ((size_t)b * N_ + n0 + row) * D_ + cg;
    int w = tid >> 6, l = tid & 63, lr = l & 15, q = l >> 4;
    f32x4 acc[4] = {};
    for (int k0 = 0; k0 < 512; k0 += 32){
        *(us8*)&As[row][cg] = *(const us8*)(pp + k0);
        *(us8*)&Bs[row][cg] = *(const us8*)(op + k0);
        __syncthreads();
        frag8 af = *(const frag8*)&As[w * 16 + lr][q * 8];
        #pragma unroll
        for (int t4 = 0; t4 < 4; ++t4){
            frag8 bfv = *(const frag8*)&Bs[t4 * 16 + lr][q * 8];
            acc[t4] = __builtin_amdgcn_mfma_f32_16x16x32_bf16(af, bfv, acc[t4], 0, 0, 0);
        }
        __syncthreads();
    }
    #pragma unroll
    for (int t4 = 0; t4 < 4; ++t4)
        #pragma unroll
        for (int r = 0; r < 4; ++r)
            po[((size_t)b * C_ + c0 + w * 16 + q * 4 + r) * N_ + n0 + t4 * 16 + lr] = acc[t4][r];
}

// ---------------- BN2 stats (fp32 input) ----------------
__global__ __launch_bounds__(256) void k_bnstats(const float* __restrict__ y, const u16* __restrict__ gamma,
                                                 const u16* __restrict__ beta, float* __restrict__ s,
                                                 float* __restrict__ t){
    int ch = blockIdx.x, tid = threadIdx.x;
    float sum = 0.f, ss = 0.f;
    for (int b = 0; b < B_; ++b){
        const float* p = y + ((size_t)b * C_ + ch) * N_;
        for (int i = tid * 4; i < N_; i += 1024){
            f32x4 v = *(const f32x4*)(p + i);
            #pragma unroll
            for (int j = 0; j < 4; ++j){ sum += v[j]; ss += v[j] * v[j]; }
        }
    }
    __shared__ float sm[8];
    for (int off = 32; off > 0; off >>= 1){ sum += __shfl_down(sum, off); ss += __shfl_down(ss, off); }
    int w = tid >> 6;
    if ((tid & 63) == 0){ sm[w] = sum; sm[4 + w] = ss; }
    __syncthreads();
    if (tid == 0){
        float S = sm[0] + sm[1] + sm[2] + sm[3];
        float Q = sm[4] + sm[5] + sm[6] + sm[7];
        float mean = S / 32768.f;
        float var = Q / 32768.f - mean * mean;
        float inv = rsqrtf(var + 1e-5f);
        float sc = b2f(gamma[ch]) * inv;
        s[ch] = sc;
        t[ch] = b2f(beta[ch]) - mean * sc;
    }
}

// ---------------- apply BN2 in place (fp32) ----------------
__global__ __launch_bounds__(256) void k_bnapply(float* __restrict__ po, const float* __restrict__ s,
                                                 const float* __restrict__ t){
    size_t idx = ((size_t)blockIdx.x * 256 + threadIdx.x) * 8;
    int c = (int)((idx >> 12) & 511);
    float sc = s[c], tc = t[c];
    f32x4 a = *(const f32x4*)(po + idx);
    f32x4 b = *(const f32x4*)(po + idx + 4);
    #pragma unroll
    for (int j = 0; j < 4; ++j){ a[j] = a[j] * sc + tc; b[j] = b[j] * sc + tc; }
    *(f32x4*)(po + idx) = a;
    *(f32x4*)(po + idx + 4) = b;
}

extern "C" void kernel_launch(void* const* d_in, const int* in_sizes, int n_in,
                              void* d_out, int out_size, void* d_ws, size_t ws_size,
                              hipStream_t stream){
    float* out = (float*)d_out;
    char* ws = (char*)d_ws;

    // ---- workspace layout, 109 MB total ----
    int*   flag  = (int*)ws;
    float* s1    = (float*)(ws + 4096);
    float* t1    = (float*)(ws + 12288);
    float* s2    = (float*)(ws + 20480);
    float* t2    = (float*)(ws + 22528);
    float* mx    = (float*)(ws + 24576);
    u16*   kmean = (u16*)(ws + 28672);                 // 8*512 bf16
    u16*   g1c   = (u16*)(ws + 36864);
    u16*   b1c   = (u16*)(ws + 40960);
    u16*   anwc  = (u16*)(ws + 45056);
    u16*   g2c   = (u16*)(ws + 46080);
    u16*   b2c   = (u16*)(ws + 47104);
    u16*   wc    = (u16*)(ws + (1ull << 20));          // 2 MB
    u16*   pc    = (u16*)(ws + (3ull << 20));          // 0.5 MB
    u16*   Gb    = (u16*)(ws + (3584ull << 10));       // 0.5 MB
    float* T     = (float*)(ws + (4ull << 20));        // 4 MB
    u16*   vkall = (u16*)(ws + (8ull << 20));          // 4 MB
    u16*   kv    = (u16*)(ws + (12ull << 20));         // 64 MB -> ends 76 MB
    u16*   og    = (u16*)(ws + (76ull << 20));         // 32 MB -> ends 108 MB
    float* Gf    = (float*)(ws + (108ull << 20));      // 1 MB -> ends 109 MB

    // ---- detect + canonicalize params/weights to bf16 ----
    k_detect<<<1, 256, 0, stream>>>((const unsigned int*)d_in[0], flag);
    k_convert<<<512, 256, 0, stream>>>(d_in[1], wc, 1048576, flag);
    k_convert<<<1, 256, 0, stream>>>(d_in[2], g1c, 2048, flag);
    k_convert<<<1, 256, 0, stream>>>(d_in[3], b1c, 2048, flag);
    k_convert<<<1, 256, 0, stream>>>(d_in[4], anwc, 512, flag);
    k_convert<<<128, 256, 0, stream>>>(d_in[5], pc, 262144, flag);
    k_convert<<<1, 256, 0, stream>>>(d_in[6], g2c, 512, flag);
    k_convert<<<1, 256, 0, stream>>>(d_in[7], b2c, 512, flag);

    // ---- BN1 from sufficient statistics (split-K Gram) ----
    hipMemsetAsync(Gf, 0, C_ * C_ * sizeof(float), stream);
    k_xmean<<<512, 256, 0, stream>>>(d_in[0], flag, mx);
    k_gram_split<<<dim3(8, 8, 32), 256, 0, stream>>>(d_in[0], flag, Gf);
    k_gram_fin<<<1024, 256, 0, stream>>>(Gf, Gb);
    k_wg<<<dim3(8, 32), 256, 0, stream>>>(wc, Gb, T);
    k_bn1fin<<<2048, 256, 0, stream>>>(T, wc, mx, g1c, b1c, s1, t1);

    // ---- phase 1: k(sigm), v ; vk + kmean ----
    k_gemm_act<1><<<dim3(64, 16, 8), 256, 0, stream>>>(wc, d_in[0], flag, s1, t1, kv);
    k_vk<<<dim3(8, 8, 8), 256, 0, stream>>>(kv, vkall);
    k_kmean<<<dim3(512, 8), 256, 0, stream>>>(kv, kmean);

    // ---- phase 2: q(sigm), g(silu) ; attn ----
    k_gemm_act<2><<<dim3(64, 16, 8), 256, 0, stream>>>(wc, d_in[0], flag, s1, t1, kv);
    k_attn<<<dim3(64, 8), 256, 0, stream>>>(kv, vkall, kmean, anwc, og);

    // ---- proj (fp32 out into d_out) + BN2 in place ----
    k_proj<<<dim3(64, 8, 8), 256, 0, stream>>>(pc, og, out);
    k_bnstats<<<512, 256, 0, stream>>>(out, g2c, b2c, s2, t2);
    k_bnapply<<<8192, 256, 0, stream>>>(out, s2, t2);
}